// Round 2
// 963.619 us; speedup vs baseline: 1.2076x; 1.2076x over previous
//
#include <hip/hip_runtime.h>
#include <hip/hip_bf16.h>
#include <stdint.h>

#define D     128
#define DPAD  136   // padded LDS row stride (bf16 elems) -> 272B
#define TM    64    // rows (edges or nodes) per block tile
#define NB    256   // blocks for the histogram sort
#define RMAX  64
#define RS    16    // staged columns in scan_kernel (R==16 in this problem)
#define NSB   128   // blocks for the N-length prefix scan
#define NST   256   // threads per scan block

typedef __bf16 bf16_t;
typedef __bf16 bf16x8 __attribute__((ext_vector_type(8)));
typedef float  f32x4  __attribute__((ext_vector_type(4)));

// ---------------- preprocessing kernels ----------------

// dst in-degree (N=100K addresses, ~10 hits each: low contention)
__global__ void deg_kernel(const int* __restrict__ ei, int E, int* __restrict__ cnt) {
    int e = blockIdx.x * blockDim.x + threadIdx.x;
    if (e < E) atomicAdd(&cnt[ei[E + e]], 1);
}

__global__ void inv_kernel(const int* __restrict__ cnt, float* __restrict__ inv, int N) {
    int n = blockIdx.x * blockDim.x + threadIdx.x;
    if (n < N) inv[n] = 1.0f / (float)max(cnt[n], 1);
}

// pass 1: per-block relation histogram over a contiguous edge chunk
__global__ void hist_kernel(const int* __restrict__ et, int E, int chunk,
                            int R, int* __restrict__ blockhist) {
    __shared__ int h[RMAX];
    int tid = threadIdx.x;
    if (tid < R) h[tid] = 0;
    __syncthreads();
    int start = blockIdx.x * chunk;
    int end   = min(E, start + chunk);
    for (int i = start + tid; i < end; i += blockDim.x)
        atomicAdd(&h[et[i]], 1);
    __syncthreads();
    if (tid < R) blockhist[blockIdx.x * R + tid] = h[tid];
}

// pass 2 (1 block): column-scan blockhist -> blockoff; rel_off; tile tables.
// blockhist staged into LDS (coalesced) so the per-relation running-sum
// chains hit LDS latency, not serial strided L2 round-trips.
__global__ void scan_kernel(int* __restrict__ blockhist, int R,
                            int* __restrict__ blockoff,
                            int* __restrict__ rel_off, int* __restrict__ tile_base,
                            int* __restrict__ tile_rel, int* __restrict__ tile_idx) {
    __shared__ int s_bh[NB * RS];          // transposed [r][b], 16 KB for R=16
    __shared__ int tot[RMAX];
    __shared__ int s_off[RMAX + 1], s_tb[RMAX + 1];
    int tid = threadIdx.x;
    const bool staged = (R <= RS);
    if (staged) {
        for (int i = tid; i < NB * R; i += blockDim.x) {
            int b = i / R, r = i - b * R;
            s_bh[r * NB + b] = blockhist[i];
        }
    }
    __syncthreads();
    if (tid < R) {
        int run = 0;
        if (staged) { for (int b = 0; b < NB; b++) run += s_bh[tid * NB + b]; }
        else        { for (int b = 0; b < NB; b++) run += blockhist[b * R + tid]; }
        tot[tid] = run;
    }
    __syncthreads();
    if (tid == 0) {
        int acc = 0, tb = 0;
        for (int r = 0; r < R; r++) {
            s_off[r] = acc; s_tb[r] = tb;
            acc += tot[r];
            tb  += (tot[r] + TM - 1) / TM;
        }
        s_off[R] = acc; s_tb[R] = tb;
    }
    __syncthreads();
    if (tid <= R) {
        rel_off[tid]   = s_off[tid];
        tile_base[tid] = s_tb[tid];
    }
    if (tid < R) {
        int run = s_off[tid];
        for (int b = 0; b < NB; b++) {
            int v = staged ? s_bh[tid * NB + b] : blockhist[b * R + tid];
            blockoff[b * R + tid] = run;
            run += v;
        }
    }
    __syncthreads();
    for (int r = 0; r < R; r++) {
        int nt = s_tb[r + 1] - s_tb[r];
        for (int t = tid; t < nt; t += blockDim.x) {
            tile_rel[s_tb[r] + t] = r;
            tile_idx[s_tb[r] + t] = t;
        }
    }
}

// pass 3: deterministic-chunk scatter, position claims via private LDS counters.
// Optionally records dst per slot (atomic fallback) and the INVERSE map
// relpos[edge] = rel-sorted position (scatter path).
__global__ void scatter2_kernel(const int* __restrict__ ei, const int* __restrict__ et,
                                int E, int chunk, int R,
                                const int* __restrict__ blockoff,
                                int* __restrict__ s_src, int* s_dst, int* relpos) {
    __shared__ int ofs[RMAX];
    int tid = threadIdx.x;
    if (tid < R) ofs[tid] = blockoff[blockIdx.x * R + tid];
    __syncthreads();
    int start = blockIdx.x * chunk;
    int end   = min(E, start + chunk);
    for (int i = start + tid; i < end; i += blockDim.x) {
        int r = et[i];
        int p = atomicAdd(&ofs[r], 1);
        s_src[p] = ei[i];
        if (s_dst) s_dst[p] = ei[E + i];
        if (relpos) relpos[i] = p;
    }
}

// ---- multi-block exclusive prefix scan over cnt[N] -> dst_off[N+1], dst_ptr ----

// A: per-block sums (coalesced)
__global__ void nsum_kernel(const int* __restrict__ cnt, int N, int chunkN,
                            int* __restrict__ bsum) {
    __shared__ int red[NST];
    int b = blockIdx.x, tid = threadIdx.x;
    int s = b * chunkN, e = min(N, s + chunkN);
    int sum = 0;
    for (int i = s + tid; i < e; i += NST) sum += cnt[i];
    red[tid] = sum;
    __syncthreads();
    for (int off = NST / 2; off > 0; off >>= 1) {
        if (tid < off) red[tid] += red[tid + off];
        __syncthreads();
    }
    if (tid == 0) bsum[b] = red[0];
}

// B: 1 tiny block — exclusive scan over the NSB block sums; total at bsum[nb]
__global__ void nscanB_kernel(int* __restrict__ bsum, int nb) {
    __shared__ int ts[NST];
    int tid = threadIdx.x;
    int v = (tid < nb) ? bsum[tid] : 0;
    ts[tid] = v;
    __syncthreads();
    for (int off = 1; off < NST; off <<= 1) {
        int t = (tid >= off) ? ts[tid - off] : 0;
        __syncthreads();
        ts[tid] += t;
        __syncthreads();
    }
    if (tid < nb) bsum[tid] = ts[tid] - v;     // exclusive
    if (tid == nb - 1) bsum[nb] = ts[tid];     // grand total
}

// C: per-block coalesced scan + write-out of dst_off/dst_ptr
__global__ void nwrite_kernel(const int* __restrict__ cnt, int N, int chunkN,
                              const int* __restrict__ bsum,
                              int* __restrict__ dst_off, int* __restrict__ dst_ptr) {
    __shared__ int tile[NST];
    __shared__ int carry;
    int b = blockIdx.x, tid = threadIdx.x;
    int s = b * chunkN, e = min(N, s + chunkN);
    if (tid == 0) carry = bsum[b];
    __syncthreads();
    for (int base = s; base < e; base += NST) {
        int i = base + tid;
        int v = (i < e) ? cnt[i] : 0;
        tile[tid] = v;
        __syncthreads();
        for (int off = 1; off < NST; off <<= 1) {
            int t = (tid >= off) ? tile[tid - off] : 0;
            __syncthreads();
            tile[tid] += t;
            __syncthreads();
        }
        int incl = tile[tid];
        int excl = carry + incl - v;
        if (i < e) { dst_off[i] = excl; dst_ptr[i] = excl; }
        __syncthreads();
        if (tid == 0) carry += tile[NST - 1];
        __syncthreads();
    }
    if (b == 0 && tid == 0) dst_off[N] = bsum[NSB];
}

// each original edge claims its dst-sorted slot and writes it straight to the
// rel-sorted msgpos table (map_kernel + dstpos round-trip eliminated)
__global__ void dstclaim_kernel(const int* __restrict__ ei, int E,
                                int* __restrict__ dst_ptr,
                                const int* __restrict__ relpos,
                                int* __restrict__ msgpos) {
    int i = blockIdx.x * blockDim.x + threadIdx.x;
    if (i < E) {
        int p = atomicAdd(&dst_ptr[ei[E + i]], 1);
        msgpos[relpos[i]] = p;
    }
}

// transpose+convert all weight matrices once: Wt[m][o][d] = (bf16)W[m][d][o]
__global__ void transpose_kernel(const float* __restrict__ W1, const float* __restrict__ root1,
                                 const float* __restrict__ W2, const float* __restrict__ root2,
                                 int R, bf16_t* __restrict__ Wt) {
    int m = blockIdx.x;  // 0..2R+1
    const float* src;
    if (m < R)            src = W1 + (size_t)m * D * D;
    else if (m < 2 * R)   src = W2 + (size_t)(m - R) * D * D;
    else if (m == 2 * R)  src = root1;
    else                  src = root2;
    bf16_t* dstp = Wt + (size_t)m * D * D;
    for (int i = threadIdx.x; i < D * D; i += blockDim.x) {
        int o = i >> 7, d = i & 127;
        dstp[i] = (bf16_t)src[d * D + o];
    }
}

// x_bf16[n][:] = (bf16)emb[entity[n]][:]
__global__ void gather_kernel(const int* __restrict__ entity, const float* __restrict__ emb,
                              bf16_t* __restrict__ x, int N) {
    int t = blockIdx.x * blockDim.x + threadIdx.x;
    if (t >= N * 16) return;
    int n = t >> 4, c = t & 15;
    const float4* src = (const float4*)(emb + (size_t)entity[n] * D) + c * 2;
    float4 a = src[0], b = src[1];
    bf16x8 v = { (bf16_t)a.x, (bf16_t)a.y, (bf16_t)a.z, (bf16_t)a.w,
                 (bf16_t)b.x, (bf16_t)b.y, (bf16_t)b.z, (bf16_t)b.w };
    *(bf16x8*)(x + (size_t)t * 8) = v;
}

// ---------------- main GEMM kernels ----------------

// scatter variant: msg = x[src] @ W[r], streamed as bf16 rows to msgs[slot] (no atomics)
__global__ __launch_bounds__(256, 3)
void edge_gemm_scatter(const bf16_t* __restrict__ x, const bf16_t* __restrict__ Wt,
                       const int* __restrict__ s_src_g, const int* __restrict__ msgpos,
                       const int* __restrict__ rel_off, const int* __restrict__ tile_base,
                       const int* __restrict__ tile_rel, const int* __restrict__ tile_idx,
                       int R, bf16_t* __restrict__ msgs) {
    __shared__ bf16_t sW[D * DPAD];
    __shared__ bf16_t sA[TM * DPAD];
    __shared__ int   sh_src[TM];
    __shared__ int   sh_slot[TM];

    int tile = blockIdx.x;
    if (tile >= tile_base[R]) return;
    int r = tile_rel[tile];
    int t = tile_idx[tile];
    int base = rel_off[r] + t * TM;
    int cntE = min(TM, rel_off[r + 1] - base);

    int tid = threadIdx.x;
    if (tid < TM) {
        int ok = tid < cntE;
        sh_src[tid]  = ok ? s_src_g[base + tid] : 0;
        sh_slot[tid] = ok ? msgpos[base + tid] : 0;
    }
    const uint4* Wg = (const uint4*)(Wt + (size_t)r * D * D);
    for (int c = tid; c < D * 16; c += 256) {
        int row = c >> 4, col = c & 15;
        *(uint4*)&sW[row * DPAD + col * 8] = Wg[c];
    }
    __syncthreads();
    for (int c = tid; c < TM * 16; c += 256) {
        int row = c >> 4, col = c & 15;
        const uint4* xr = (const uint4*)(x + (size_t)sh_src[row] * D);
        *(uint4*)&sA[row * DPAD + col * 8] = xr[col];
    }
    __syncthreads();

    int lane = tid & 63;
    int w = tid >> 6;
    int m = lane & 15, q = lane >> 4;
    f32x4 acc[4][2];
#pragma unroll
    for (int a = 0; a < 4; a++)
#pragma unroll
        for (int b = 0; b < 2; b++) acc[a][b] = (f32x4){0.f, 0.f, 0.f, 0.f};

#pragma unroll
    for (int k0 = 0; k0 < D; k0 += 32) {
        bf16x8 af[4], bfr[2];
#pragma unroll
        for (int mt = 0; mt < 4; mt++)
            af[mt] = *(const bf16x8*)&sA[(mt * 16 + m) * DPAD + k0 + q * 8];
#pragma unroll
        for (int nt = 0; nt < 2; nt++)
            bfr[nt] = *(const bf16x8*)&sW[(w * 32 + nt * 16 + m) * DPAD + k0 + q * 8];
#pragma unroll
        for (int mt = 0; mt < 4; mt++)
#pragma unroll
            for (int nt = 0; nt < 2; nt++)
                acc[mt][nt] = __builtin_amdgcn_mfma_f32_16x16x32_bf16(af[mt], bfr[nt], acc[mt][nt], 0, 0, 0);
    }

    // epilogue: repack acc -> row-major bf16 in LDS (reuse sA), stream rows out
    __syncthreads();
#pragma unroll
    for (int mt = 0; mt < 4; mt++)
#pragma unroll
        for (int i = 0; i < 4; i++) {
            int row = mt * 16 + q * 4 + i;
#pragma unroll
            for (int nt = 0; nt < 2; nt++)
                sA[row * DPAD + w * 32 + nt * 16 + m] = (bf16_t)acc[mt][nt][i];
        }
    __syncthreads();
    for (int c = tid; c < cntE * 16; c += 256) {
        int row = c >> 4, col = c & 15;
        ((uint4*)msgs)[(size_t)sh_slot[row] * 16 + col] = *(uint4*)&sA[row * DPAD + col * 8];
    }
}

// atomic fallback (used only if workspace too small for msgs)
__global__ __launch_bounds__(256, 3)
void edge_gemm_atomic(const bf16_t* __restrict__ x, const bf16_t* __restrict__ Wt,
                      const int* __restrict__ s_src_g, const int* __restrict__ s_dst_g,
                      const float* __restrict__ inv_cnt,
                      const int* __restrict__ rel_off, const int* __restrict__ tile_base,
                      const int* __restrict__ tile_rel, const int* __restrict__ tile_idx,
                      int R, float* __restrict__ agg) {
    __shared__ bf16_t sW[D * DPAD];
    __shared__ bf16_t sA[TM * DPAD];
    __shared__ int   sh_src[TM];
    __shared__ int   sh_dst[TM];
    __shared__ float sh_inv[TM];

    int tile = blockIdx.x;
    if (tile >= tile_base[R]) return;
    int r = tile_rel[tile];
    int t = tile_idx[tile];
    int base = rel_off[r] + t * TM;
    int cntE = min(TM, rel_off[r + 1] - base);

    int tid = threadIdx.x;
    if (tid < TM) {
        int ok = tid < cntE;
        int s  = ok ? s_src_g[base + tid] : 0;
        int dd = ok ? s_dst_g[base + tid] : 0;
        sh_src[tid] = s;
        sh_dst[tid] = dd;
        sh_inv[tid] = ok ? inv_cnt[dd] : 0.f;
    }
    const uint4* Wg = (const uint4*)(Wt + (size_t)r * D * D);
    for (int c = tid; c < D * 16; c += 256) {
        int row = c >> 4, col = c & 15;
        *(uint4*)&sW[row * DPAD + col * 8] = Wg[c];
    }
    __syncthreads();
    for (int c = tid; c < TM * 16; c += 256) {
        int row = c >> 4, col = c & 15;
        const uint4* xr = (const uint4*)(x + (size_t)sh_src[row] * D);
        *(uint4*)&sA[row * DPAD + col * 8] = xr[col];
    }
    __syncthreads();

    int lane = tid & 63;
    int w = tid >> 6;
    int m = lane & 15, q = lane >> 4;
    f32x4 acc[4][2];
#pragma unroll
    for (int a = 0; a < 4; a++)
#pragma unroll
        for (int b = 0; b < 2; b++) acc[a][b] = (f32x4){0.f, 0.f, 0.f, 0.f};

#pragma unroll
    for (int k0 = 0; k0 < D; k0 += 32) {
        bf16x8 af[4], bfr[2];
#pragma unroll
        for (int mt = 0; mt < 4; mt++)
            af[mt] = *(const bf16x8*)&sA[(mt * 16 + m) * DPAD + k0 + q * 8];
#pragma unroll
        for (int nt = 0; nt < 2; nt++)
            bfr[nt] = *(const bf16x8*)&sW[(w * 32 + nt * 16 + m) * DPAD + k0 + q * 8];
#pragma unroll
        for (int mt = 0; mt < 4; mt++)
#pragma unroll
            for (int nt = 0; nt < 2; nt++)
                acc[mt][nt] = __builtin_amdgcn_mfma_f32_16x16x32_bf16(af[mt], bfr[nt], acc[mt][nt], 0, 0, 0);
    }

#pragma unroll
    for (int mt = 0; mt < 4; mt++)
#pragma unroll
        for (int i = 0; i < 4; i++) {
            int edge = mt * 16 + q * 4 + i;
            if (edge < cntE) {
                float sc = sh_inv[edge];
                float* ag = agg + (size_t)sh_dst[edge] * D;
#pragma unroll
                for (int nt = 0; nt < 2; nt++) {
                    int o = w * 32 + nt * 16 + m;
                    atomicAdd(&ag[o], acc[mt][nt][i] * sc);
                }
            }
        }
}

// coalesced segmented sum: agg[n] = inv[n] * sum of msgs rows [dst_off[n], dst_off[n+1])
__global__ __launch_bounds__(256)
void seg_sum(const bf16_t* __restrict__ msgs, const int* __restrict__ dst_off,
             const float* __restrict__ inv, float* __restrict__ agg, int N) {
    int node = blockIdx.x * 16 + (threadIdx.x >> 4);
    int t = threadIdx.x & 15;
    if (node >= N) return;
    int s = dst_off[node], e = dst_off[node + 1];
    float sum[8] = {0.f, 0.f, 0.f, 0.f, 0.f, 0.f, 0.f, 0.f};
    for (int j = s; j < e; j++) {
        bf16x8 v = *(const bf16x8*)(msgs + (size_t)j * D + t * 8);
#pragma unroll
        for (int k = 0; k < 8; k++) sum[k] += (float)v[k];
    }
    float sc = inv[node];
    float* out = agg + (size_t)node * D + t * 8;
    *(float4*)out       = (float4){sum[0] * sc, sum[1] * sc, sum[2] * sc, sum[3] * sc};
    *(float4*)(out + 4) = (float4){sum[4] * sc, sum[5] * sc, sum[6] * sc, sum[7] * sc};
}

// out[n] = (relu?)( x[n] @ root + agg[n] )
__global__ __launch_bounds__(256, 3)
void root_gemm(const bf16_t* x, const bf16_t* __restrict__ roott,
               const float* __restrict__ agg, bf16_t* out16, float* out32,
               int N, int relu) {
    __shared__ bf16_t sW[D * DPAD];
    __shared__ bf16_t sA[TM * DPAD];
    int tid = threadIdx.x;
    int nbase = blockIdx.x * TM;

    const uint4* Wg = (const uint4*)roott;
    for (int c = tid; c < D * 16; c += 256) {
        int row = c >> 4, col = c & 15;
        *(uint4*)&sW[row * DPAD + col * 8] = Wg[c];
    }
    for (int c = tid; c < TM * 16; c += 256) {
        int row = c >> 4, col = c & 15;
        int n = nbase + row;
        if (n >= N) n = N - 1;
        *(uint4*)&sA[row * DPAD + col * 8] = ((const uint4*)(x + (size_t)n * D))[col];
    }
    __syncthreads();

    int lane = tid & 63;
    int w = tid >> 6;
    int m = lane & 15, q = lane >> 4;
    f32x4 acc[4][2];
#pragma unroll
    for (int a = 0; a < 4; a++)
#pragma unroll
        for (int b = 0; b < 2; b++) acc[a][b] = (f32x4){0.f, 0.f, 0.f, 0.f};

#pragma unroll
    for (int k0 = 0; k0 < D; k0 += 32) {
        bf16x8 af[4], bfr[2];
#pragma unroll
        for (int mt = 0; mt < 4; mt++)
            af[mt] = *(const bf16x8*)&sA[(mt * 16 + m) * DPAD + k0 + q * 8];
#pragma unroll
        for (int nt = 0; nt < 2; nt++)
            bfr[nt] = *(const bf16x8*)&sW[(w * 32 + nt * 16 + m) * DPAD + k0 + q * 8];
#pragma unroll
        for (int mt = 0; mt < 4; mt++)
#pragma unroll
            for (int nt = 0; nt < 2; nt++)
                acc[mt][nt] = __builtin_amdgcn_mfma_f32_16x16x32_bf16(af[mt], bfr[nt], acc[mt][nt], 0, 0, 0);
    }

#pragma unroll
    for (int mt = 0; mt < 4; mt++)
#pragma unroll
        for (int i = 0; i < 4; i++) {
            int row = mt * 16 + q * 4 + i;
            int n = nbase + row;
            if (n < N) {
#pragma unroll
                for (int nt = 0; nt < 2; nt++) {
                    int o = w * 32 + nt * 16 + m;
                    float v = acc[mt][nt][i] + agg[(size_t)n * D + o];
                    if (relu) v = fmaxf(v, 0.f);
                    if (out16) out16[(size_t)n * D + o] = (bf16_t)v;
                    else       out32[(size_t)n * D + o] = v;
                }
            }
        }
}

// ---------------- host launcher ----------------

extern "C" void kernel_launch(void* const* d_in, const int* in_sizes, int n_in,
                              void* d_out, int out_size, void* d_ws, size_t ws_size,
                              hipStream_t stream) {
    const int*   entity = (const int*)d_in[0];
    const int*   ei     = (const int*)d_in[1];   // [2,E]: row0=src, row1=dst
    const int*   et     = (const int*)d_in[2];
    const float* emb    = (const float*)d_in[4];
    const float* W1     = (const float*)d_in[5];
    const float* root1  = (const float*)d_in[6];
    const float* W2     = (const float*)d_in[7];
    const float* root2  = (const float*)d_in[8];

    const int N = in_sizes[0];
    const int E = in_sizes[2];
    const int R = in_sizes[5] / (D * D);

    char* p = (char*)d_ws;
    auto alloc = [&](size_t bytes) -> char* {
        char* q = p; p += (bytes + 255) & ~(size_t)255; return q;
    };
    // common region
    float*  agg      = (float*)alloc((size_t)N * D * 4);
    bf16_t* x        = (bf16_t*)alloc((size_t)N * D * 2);
    bf16_t* Wt       = (bf16_t*)alloc((size_t)(2 * R + 2) * D * D * 2);
    int*    s_src    = (int*)alloc((size_t)E * 4);
    int*    cnt      = (int*)alloc((size_t)N * 4);
    float*  inv      = (float*)alloc((size_t)N * 4);
    int*    blockhist= (int*)alloc((size_t)NB * R * 4);
    int*    blockoff = (int*)alloc((size_t)NB * R * 4);
    int*    rel_off  = (int*)alloc((size_t)(R + 1) * 4);
    int*    tile_bs  = (int*)alloc((size_t)(R + 1) * 4);
    const int maxtiles = (E + TM - 1) / TM + R;
    int*    tile_rel = (int*)alloc((size_t)maxtiles * 4);
    int*    tile_idx = (int*)alloc((size_t)maxtiles * 4);
    char*   p_common = p;

    // scatter-path extras
    bf16_t* msgs    = (bf16_t*)alloc((size_t)E * D * 2);
    int*    relpos  = (int*)alloc((size_t)E * 4);
    int*    msgpos  = (int*)alloc((size_t)E * 4);
    int*    dst_off = (int*)alloc((size_t)(N + 1) * 4);
    int*    dst_ptr = (int*)alloc((size_t)N * 4);
    int*    bsum    = (int*)alloc((size_t)(NSB + 1) * 4);
    bool big = ((size_t)(p - (char*)d_ws) <= ws_size);

    int* s_dst = nullptr;
    if (!big) { p = p_common; s_dst = (int*)alloc((size_t)E * 4); }

    const int chunk = (E + NB - 1) / NB;

    // shared preprocessing
    hipMemsetAsync(cnt, 0, (size_t)N * 4, stream);
    deg_kernel<<<(E + 255) / 256, 256, 0, stream>>>(ei, E, cnt);
    inv_kernel<<<(N + 255) / 256, 256, 0, stream>>>(cnt, inv, N);
    hist_kernel<<<NB, 256, 0, stream>>>(et, E, chunk, R, blockhist);
    scan_kernel<<<1, 256, 0, stream>>>(blockhist, R, blockoff, rel_off, tile_bs, tile_rel, tile_idx);
    scatter2_kernel<<<NB, 256, 0, stream>>>(ei, et, E, chunk, R, blockoff,
                                            s_src, big ? nullptr : s_dst, big ? relpos : nullptr);
    transpose_kernel<<<2 * R + 2, 256, 0, stream>>>(W1, root1, W2, root2, R, Wt);
    gather_kernel<<<(N * 16 + 255) / 256, 256, 0, stream>>>(entity, emb, x, N);

    if (big) {
        const int chunkN = (N + NSB - 1) / NSB;
        nsum_kernel<<<NSB, NST, 0, stream>>>(cnt, N, chunkN, bsum);
        nscanB_kernel<<<1, NST, 0, stream>>>(bsum, NSB);
        nwrite_kernel<<<NSB, NST, 0, stream>>>(cnt, N, chunkN, bsum, dst_off, dst_ptr);
        dstclaim_kernel<<<(E + 255) / 256, 256, 0, stream>>>(ei, E, dst_ptr, relpos, msgpos);

        // layer 1
        edge_gemm_scatter<<<maxtiles, 256, 0, stream>>>(x, Wt, s_src, msgpos,
                                                        rel_off, tile_bs, tile_rel, tile_idx, R, msgs);
        seg_sum<<<(N + 15) / 16, 256, 0, stream>>>(msgs, dst_off, inv, agg, N);
        root_gemm<<<(N + TM - 1) / TM, 256, 0, stream>>>(x, Wt + (size_t)(2 * R) * D * D, agg,
                                                         x, (float*)nullptr, N, 1);
        // layer 2
        edge_gemm_scatter<<<maxtiles, 256, 0, stream>>>(x, Wt + (size_t)R * D * D, s_src, msgpos,
                                                        rel_off, tile_bs, tile_rel, tile_idx, R, msgs);
        seg_sum<<<(N + 15) / 16, 256, 0, stream>>>(msgs, dst_off, inv, agg, N);
        root_gemm<<<(N + TM - 1) / TM, 256, 0, stream>>>(x, Wt + (size_t)(2 * R + 1) * D * D, agg,
                                                         (bf16_t*)nullptr, (float*)d_out, N, 0);
    } else {
        // atomic fallback
        hipMemsetAsync(agg, 0, (size_t)N * D * 4, stream);
        edge_gemm_atomic<<<maxtiles, 256, 0, stream>>>(x, Wt, s_src, s_dst, inv,
                                                       rel_off, tile_bs, tile_rel, tile_idx, R, agg);
        root_gemm<<<(N + TM - 1) / TM, 256, 0, stream>>>(x, Wt + (size_t)(2 * R) * D * D, agg,
                                                         x, (float*)nullptr, N, 1);
        hipMemsetAsync(agg, 0, (size_t)N * D * 4, stream);
        edge_gemm_atomic<<<maxtiles, 256, 0, stream>>>(x, Wt + (size_t)R * D * D, s_src, s_dst, inv,
                                                       rel_off, tile_bs, tile_rel, tile_idx, R, agg);
        root_gemm<<<(N + TM - 1) / TM, 256, 0, stream>>>(x, Wt + (size_t)(2 * R + 1) * D * D, agg,
                                                         (bf16_t*)nullptr, (float*)d_out, N, 0);
    }
}

// Round 3
// 953.410 us; speedup vs baseline: 1.2205x; 1.0107x over previous
//
#include <hip/hip_runtime.h>
#include <hip/hip_bf16.h>
#include <stdint.h>

#define D     128
#define DPAD  136   // padded LDS row stride (bf16 elems) -> 272B
#define TME   128   // edge rows per block tile (edge GEMM)
#define NB    256   // blocks for the histogram sort
#define RMAX  64
#define RS    16    // staged columns in scan_kernel (R==16 in this problem)
#define NSB   128   // blocks for the N-length prefix scan
#define NST   256   // threads per scan block
#define AST   132   // f32 LDS row stride in fused seg+root kernel

typedef __bf16 bf16_t;
typedef __bf16 bf16x8 __attribute__((ext_vector_type(8)));
typedef float  f32x4  __attribute__((ext_vector_type(4)));

// ---------------- preprocessing kernels ----------------

// merged: per-block relation histogram + dst in-degree (one pass over edges)
__global__ void hist_kernel(const int* __restrict__ ei, const int* __restrict__ et,
                            int E, int chunk, int R,
                            int* __restrict__ blockhist, int* __restrict__ cnt) {
    __shared__ int h[RMAX];
    int tid = threadIdx.x;
    if (tid < R) h[tid] = 0;
    __syncthreads();
    int start = blockIdx.x * chunk;
    int end   = min(E, start + chunk);
    for (int i = start + tid; i < end; i += blockDim.x) {
        atomicAdd(&h[et[i]], 1);
        atomicAdd(&cnt[ei[E + i]], 1);
    }
    __syncthreads();
    if (tid < R) blockhist[blockIdx.x * R + tid] = h[tid];
}

__global__ void inv_kernel(const int* __restrict__ cnt, float* __restrict__ inv, int N) {
    int n = blockIdx.x * blockDim.x + threadIdx.x;
    if (n < N) inv[n] = 1.0f / (float)max(cnt[n], 1);
}

// pass 2 (1 block): column-scan blockhist -> blockoff; rel_off; tile tables.
__global__ void scan_kernel(int* __restrict__ blockhist, int R,
                            int* __restrict__ blockoff,
                            int* __restrict__ rel_off, int* __restrict__ tile_base,
                            int* __restrict__ tile_rel, int* __restrict__ tile_idx) {
    __shared__ int s_bh[NB * RS];          // transposed [r][b], 16 KB for R=16
    __shared__ int tot[RMAX];
    __shared__ int s_off[RMAX + 1], s_tb[RMAX + 1];
    int tid = threadIdx.x;
    const bool staged = (R <= RS);
    if (staged) {
        for (int i = tid; i < NB * R; i += blockDim.x) {
            int b = i / R, r = i - b * R;
            s_bh[r * NB + b] = blockhist[i];
        }
    }
    __syncthreads();
    if (tid < R) {
        int run = 0;
        if (staged) { for (int b = 0; b < NB; b++) run += s_bh[tid * NB + b]; }
        else        { for (int b = 0; b < NB; b++) run += blockhist[b * R + tid]; }
        tot[tid] = run;
    }
    __syncthreads();
    if (tid == 0) {
        int acc = 0, tb = 0;
        for (int r = 0; r < R; r++) {
            s_off[r] = acc; s_tb[r] = tb;
            acc += tot[r];
            tb  += (tot[r] + TME - 1) / TME;
        }
        s_off[R] = acc; s_tb[R] = tb;
    }
    __syncthreads();
    if (tid <= R) {
        rel_off[tid]   = s_off[tid];
        tile_base[tid] = s_tb[tid];
    }
    if (tid < R) {
        int run = s_off[tid];
        for (int b = 0; b < NB; b++) {
            int v = staged ? s_bh[tid * NB + b] : blockhist[b * R + tid];
            blockoff[b * R + tid] = run;
            run += v;
        }
    }
    __syncthreads();
    for (int r = 0; r < R; r++) {
        int nt = s_tb[r + 1] - s_tb[r];
        for (int t = tid; t < nt; t += blockDim.x) {
            tile_rel[s_tb[r] + t] = r;
            tile_idx[s_tb[r] + t] = t;
        }
    }
}

// pass 3: deterministic-chunk scatter, position claims via private LDS counters.
__global__ void scatter2_kernel(const int* __restrict__ ei, const int* __restrict__ et,
                                int E, int chunk, int R,
                                const int* __restrict__ blockoff,
                                int* __restrict__ s_src, int* s_dst, int* relpos) {
    __shared__ int ofs[RMAX];
    int tid = threadIdx.x;
    if (tid < R) ofs[tid] = blockoff[blockIdx.x * R + tid];
    __syncthreads();
    int start = blockIdx.x * chunk;
    int end   = min(E, start + chunk);
    for (int i = start + tid; i < end; i += blockDim.x) {
        int r = et[i];
        int p = atomicAdd(&ofs[r], 1);
        s_src[p] = ei[i];
        if (s_dst) s_dst[p] = ei[E + i];
        if (relpos) relpos[i] = p;
    }
}

// ---- multi-block exclusive prefix scan over cnt[N] -> dst_off[N+1], dst_ptr ----

__global__ void nsum_kernel(const int* __restrict__ cnt, int N, int chunkN,
                            int* __restrict__ bsum) {
    __shared__ int red[NST];
    int b = blockIdx.x, tid = threadIdx.x;
    int s = b * chunkN, e = min(N, s + chunkN);
    int sum = 0;
    for (int i = s + tid; i < e; i += NST) sum += cnt[i];
    red[tid] = sum;
    __syncthreads();
    for (int off = NST / 2; off > 0; off >>= 1) {
        if (tid < off) red[tid] += red[tid + off];
        __syncthreads();
    }
    if (tid == 0) bsum[b] = red[0];
}

__global__ void nscanB_kernel(int* __restrict__ bsum, int nb) {
    __shared__ int ts[NST];
    int tid = threadIdx.x;
    int v = (tid < nb) ? bsum[tid] : 0;
    ts[tid] = v;
    __syncthreads();
    for (int off = 1; off < NST; off <<= 1) {
        int t = (tid >= off) ? ts[tid - off] : 0;
        __syncthreads();
        ts[tid] += t;
        __syncthreads();
    }
    if (tid < nb) bsum[tid] = ts[tid] - v;     // exclusive
    if (tid == nb - 1) bsum[nb] = ts[tid];     // grand total
}

__global__ void nwrite_kernel(const int* __restrict__ cnt, int N, int chunkN,
                              const int* __restrict__ bsum,
                              int* __restrict__ dst_off, int* __restrict__ dst_ptr) {
    __shared__ int tile[NST];
    __shared__ int carry;
    int b = blockIdx.x, tid = threadIdx.x;
    int s = b * chunkN, e = min(N, s + chunkN);
    if (tid == 0) carry = bsum[b];
    __syncthreads();
    for (int base = s; base < e; base += NST) {
        int i = base + tid;
        int v = (i < e) ? cnt[i] : 0;
        tile[tid] = v;
        __syncthreads();
        for (int off = 1; off < NST; off <<= 1) {
            int t = (tid >= off) ? tile[tid - off] : 0;
            __syncthreads();
            tile[tid] += t;
            __syncthreads();
        }
        int incl = tile[tid];
        int excl = carry + incl - v;
        if (i < e) { dst_off[i] = excl; dst_ptr[i] = excl; }
        __syncthreads();
        if (tid == 0) carry += tile[NST - 1];
        __syncthreads();
    }
    if (b == 0 && tid == 0) dst_off[N] = bsum[NSB];
}

// each original edge claims its dst-sorted slot -> straight into msgpos
__global__ void dstclaim_kernel(const int* __restrict__ ei, int E,
                                int* __restrict__ dst_ptr,
                                const int* __restrict__ relpos,
                                int* __restrict__ msgpos) {
    int i = blockIdx.x * blockDim.x + threadIdx.x;
    if (i < E) {
        int p = atomicAdd(&dst_ptr[ei[E + i]], 1);
        msgpos[relpos[i]] = p;
    }
}

// transpose+convert all weight matrices once: Wt[m][o][d] = (bf16)W[m][d][o]
__global__ void transpose_kernel(const float* __restrict__ W1, const float* __restrict__ root1,
                                 const float* __restrict__ W2, const float* __restrict__ root2,
                                 int R, bf16_t* __restrict__ Wt) {
    int m = blockIdx.x;  // 0..2R+1
    const float* src;
    if (m < R)            src = W1 + (size_t)m * D * D;
    else if (m < 2 * R)   src = W2 + (size_t)(m - R) * D * D;
    else if (m == 2 * R)  src = root1;
    else                  src = root2;
    bf16_t* dstp = Wt + (size_t)m * D * D;
    for (int i = threadIdx.x; i < D * D; i += blockDim.x) {
        int o = i >> 7, d = i & 127;
        dstp[i] = (bf16_t)src[d * D + o];
    }
}

// x_bf16[n][:] = (bf16)emb[entity[n]][:]
__global__ void gather_kernel(const int* __restrict__ entity, const float* __restrict__ emb,
                              bf16_t* __restrict__ x, int N) {
    int t = blockIdx.x * blockDim.x + threadIdx.x;
    if (t >= N * 16) return;
    int n = t >> 4, c = t & 15;
    const float4* src = (const float4*)(emb + (size_t)entity[n] * D) + c * 2;
    float4 a = src[0], b = src[1];
    bf16x8 v = { (bf16_t)a.x, (bf16_t)a.y, (bf16_t)a.z, (bf16_t)a.w,
                 (bf16_t)b.x, (bf16_t)b.y, (bf16_t)b.z, (bf16_t)b.w };
    *(bf16x8*)(x + (size_t)t * 8) = v;
}

// ---------------- main GEMM kernels ----------------

// scatter variant: msg = x[src] @ W[r], 128-row tiles, streamed to msgs[slot]
__global__ __launch_bounds__(256, 2)
void edge_gemm_scatter(const bf16_t* __restrict__ x, const bf16_t* __restrict__ Wt,
                       const int* __restrict__ s_src_g, const int* __restrict__ msgpos,
                       const int* __restrict__ rel_off, const int* __restrict__ tile_base,
                       const int* __restrict__ tile_rel, const int* __restrict__ tile_idx,
                       int R, bf16_t* __restrict__ msgs) {
    __shared__ bf16_t sW[D * DPAD];
    __shared__ bf16_t sA[TME * DPAD];
    __shared__ int   sh_src[TME];
    __shared__ int   sh_slot[TME];

    int tile = blockIdx.x;
    if (tile >= tile_base[R]) return;
    int r = tile_rel[tile];
    int t = tile_idx[tile];
    int base = rel_off[r] + t * TME;
    int cntE = min(TME, rel_off[r + 1] - base);

    int tid = threadIdx.x;
    if (tid < TME) {
        int ok = tid < cntE;
        sh_src[tid]  = ok ? s_src_g[base + tid] : 0;
        sh_slot[tid] = ok ? msgpos[base + tid] : 0;
    }
    const uint4* Wg = (const uint4*)(Wt + (size_t)r * D * D);
    for (int c = tid; c < D * 16; c += 256) {
        int row = c >> 4, col = c & 15;
        *(uint4*)&sW[row * DPAD + col * 8] = Wg[c];
    }
    __syncthreads();
    for (int c = tid; c < TME * 16; c += 256) {
        int row = c >> 4, col = c & 15;
        const uint4* xr = (const uint4*)(x + (size_t)sh_src[row] * D);
        *(uint4*)&sA[row * DPAD + col * 8] = xr[col];
    }
    __syncthreads();

    int lane = tid & 63;
    int w = tid >> 6;
    int m = lane & 15, q = lane >> 4;
    f32x4 acc[8][2];
#pragma unroll
    for (int a = 0; a < 8; a++)
#pragma unroll
        for (int b = 0; b < 2; b++) acc[a][b] = (f32x4){0.f, 0.f, 0.f, 0.f};

#pragma unroll
    for (int k0 = 0; k0 < D; k0 += 32) {
        bf16x8 af[8], bfr[2];
#pragma unroll
        for (int mt = 0; mt < 8; mt++)
            af[mt] = *(const bf16x8*)&sA[(mt * 16 + m) * DPAD + k0 + q * 8];
#pragma unroll
        for (int nt = 0; nt < 2; nt++)
            bfr[nt] = *(const bf16x8*)&sW[(w * 32 + nt * 16 + m) * DPAD + k0 + q * 8];
#pragma unroll
        for (int mt = 0; mt < 8; mt++)
#pragma unroll
            for (int nt = 0; nt < 2; nt++)
                acc[mt][nt] = __builtin_amdgcn_mfma_f32_16x16x32_bf16(af[mt], bfr[nt], acc[mt][nt], 0, 0, 0);
    }

    // epilogue: repack acc -> row-major bf16 in LDS (reuse sA), stream rows out
    __syncthreads();
#pragma unroll
    for (int mt = 0; mt < 8; mt++)
#pragma unroll
        for (int i = 0; i < 4; i++) {
            int row = mt * 16 + q * 4 + i;
#pragma unroll
            for (int nt = 0; nt < 2; nt++)
                sA[row * DPAD + w * 32 + nt * 16 + m] = (bf16_t)acc[mt][nt][i];
        }
    __syncthreads();
    for (int c = tid; c < cntE * 16; c += 256) {
        int row = c >> 4, col = c & 15;
        ((uint4*)msgs)[(size_t)sh_slot[row] * 16 + col] = *(uint4*)&sA[row * DPAD + col * 8];
    }
}

// atomic fallback (used only if workspace too small for msgs), 128-row tiles
__global__ __launch_bounds__(256, 2)
void edge_gemm_atomic(const bf16_t* __restrict__ x, const bf16_t* __restrict__ Wt,
                      const int* __restrict__ s_src_g, const int* __restrict__ s_dst_g,
                      const float* __restrict__ inv_cnt,
                      const int* __restrict__ rel_off, const int* __restrict__ tile_base,
                      const int* __restrict__ tile_rel, const int* __restrict__ tile_idx,
                      int R, float* __restrict__ agg) {
    __shared__ bf16_t sW[D * DPAD];
    __shared__ bf16_t sA[TME * DPAD];
    __shared__ int   sh_src[TME];
    __shared__ int   sh_dst[TME];
    __shared__ float sh_inv[TME];

    int tile = blockIdx.x;
    if (tile >= tile_base[R]) return;
    int r = tile_rel[tile];
    int t = tile_idx[tile];
    int base = rel_off[r] + t * TME;
    int cntE = min(TME, rel_off[r + 1] - base);

    int tid = threadIdx.x;
    if (tid < TME) {
        int ok = tid < cntE;
        int s  = ok ? s_src_g[base + tid] : 0;
        int dd = ok ? s_dst_g[base + tid] : 0;
        sh_src[tid] = s;
        sh_dst[tid] = dd;
        sh_inv[tid] = ok ? inv_cnt[dd] : 0.f;
    }
    const uint4* Wg = (const uint4*)(Wt + (size_t)r * D * D);
    for (int c = tid; c < D * 16; c += 256) {
        int row = c >> 4, col = c & 15;
        *(uint4*)&sW[row * DPAD + col * 8] = Wg[c];
    }
    __syncthreads();
    for (int c = tid; c < TME * 16; c += 256) {
        int row = c >> 4, col = c & 15;
        const uint4* xr = (const uint4*)(x + (size_t)sh_src[row] * D);
        *(uint4*)&sA[row * DPAD + col * 8] = xr[col];
    }
    __syncthreads();

    int lane = tid & 63;
    int w = tid >> 6;
    int m = lane & 15, q = lane >> 4;
    f32x4 acc[8][2];
#pragma unroll
    for (int a = 0; a < 8; a++)
#pragma unroll
        for (int b = 0; b < 2; b++) acc[a][b] = (f32x4){0.f, 0.f, 0.f, 0.f};

#pragma unroll
    for (int k0 = 0; k0 < D; k0 += 32) {
        bf16x8 af[8], bfr[2];
#pragma unroll
        for (int mt = 0; mt < 8; mt++)
            af[mt] = *(const bf16x8*)&sA[(mt * 16 + m) * DPAD + k0 + q * 8];
#pragma unroll
        for (int nt = 0; nt < 2; nt++)
            bfr[nt] = *(const bf16x8*)&sW[(w * 32 + nt * 16 + m) * DPAD + k0 + q * 8];
#pragma unroll
        for (int mt = 0; mt < 8; mt++)
#pragma unroll
            for (int nt = 0; nt < 2; nt++)
                acc[mt][nt] = __builtin_amdgcn_mfma_f32_16x16x32_bf16(af[mt], bfr[nt], acc[mt][nt], 0, 0, 0);
    }

#pragma unroll
    for (int mt = 0; mt < 8; mt++)
#pragma unroll
        for (int i = 0; i < 4; i++) {
            int edge = mt * 16 + q * 4 + i;
            if (edge < cntE) {
                float sc = sh_inv[edge];
                float* ag = agg + (size_t)sh_dst[edge] * D;
#pragma unroll
                for (int nt = 0; nt < 2; nt++) {
                    int o = w * 32 + nt * 16 + m;
                    atomicAdd(&ag[o], acc[mt][nt][i] * sc);
                }
            }
        }
}

// fused: agg = seg-mean(msgs rows of this block's 64 nodes, contiguous in dst order)
//        out = (relu?)( x @ root + agg )
// LDS pool time-shared: phase1 f32 agg[64][AST] -> (acc preload) -> phase2 sW+sA bf16.
__global__ __launch_bounds__(256, 3)
void seg_root_gemm(const bf16_t* __restrict__ msgs, const int* __restrict__ dst_off,
                   const bf16_t* __restrict__ x, const bf16_t* __restrict__ roott,
                   bf16_t* out16, float* out32, int N, int relu) {
    __shared__ __attribute__((aligned(16))) char pool[(D + 64) * DPAD * 2]; // 52224 B
    __shared__ int s_off[65];
    float*  aggL = (float*)pool;                       // [64][AST] f32 (33792 B)
    bf16_t* sW   = (bf16_t*)pool;                      // [128][DPAD]
    bf16_t* sA   = (bf16_t*)(pool + (size_t)D * DPAD * 2); // [64][DPAD]

    int tid = threadIdx.x;
    int nbase = blockIdx.x * 64;
    if (tid < 65) s_off[tid] = dst_off[min(nbase + tid, N)];
    __syncthreads();

    // phase 1: segmented mean into aggL (16 threads per node, 4 passes)
#pragma unroll
    for (int pass = 0; pass < 4; pass++) {
        int local = pass * 16 + (tid >> 4);
        int t = tid & 15;
        int s = s_off[local], e = s_off[local + 1];
        float sum[8] = {0.f, 0.f, 0.f, 0.f, 0.f, 0.f, 0.f, 0.f};
        for (int j = s; j < e; j++) {
            bf16x8 v = *(const bf16x8*)(msgs + (size_t)j * D + t * 8);
#pragma unroll
            for (int k = 0; k < 8; k++) sum[k] += (float)v[k];
        }
        float sc = 1.0f / (float)max(e - s, 1);
        float* o = aggL + local * AST + t * 8;
        *(f32x4*)o       = (f32x4){sum[0] * sc, sum[1] * sc, sum[2] * sc, sum[3] * sc};
        *(f32x4*)(o + 4) = (f32x4){sum[4] * sc, sum[5] * sc, sum[6] * sc, sum[7] * sc};
    }
    __syncthreads();

    // phase 2a: preload accumulators from aggL (static indices)
    int lane = tid & 63;
    int w = tid >> 6;
    int m = lane & 15, q = lane >> 4;
    f32x4 acc[4][2];
#pragma unroll
    for (int mt = 0; mt < 4; mt++)
#pragma unroll
        for (int nt = 0; nt < 2; nt++)
#pragma unroll
            for (int i = 0; i < 4; i++)
                acc[mt][nt][i] = aggL[(mt * 16 + q * 4 + i) * AST + (w * 32 + nt * 16 + m)];
    __syncthreads();   // all reads of aggL done before pool is overwritten

    // phase 2b: stage root weights + x rows into the pool
    const uint4* Wg = (const uint4*)roott;
    for (int c = tid; c < D * 16; c += 256) {
        int row = c >> 4, col = c & 15;
        *(uint4*)&sW[row * DPAD + col * 8] = Wg[c];
    }
    for (int c = tid; c < 64 * 16; c += 256) {
        int row = c >> 4, col = c & 15;
        int n = nbase + row;
        if (n >= N) n = N - 1;
        *(uint4*)&sA[row * DPAD + col * 8] = ((const uint4*)(x + (size_t)n * D))[col];
    }
    __syncthreads();

    // MFMA accumulates x@root on top of the preloaded agg
#pragma unroll
    for (int k0 = 0; k0 < D; k0 += 32) {
        bf16x8 af[4], bfr[2];
#pragma unroll
        for (int mt = 0; mt < 4; mt++)
            af[mt] = *(const bf16x8*)&sA[(mt * 16 + m) * DPAD + k0 + q * 8];
#pragma unroll
        for (int nt = 0; nt < 2; nt++)
            bfr[nt] = *(const bf16x8*)&sW[(w * 32 + nt * 16 + m) * DPAD + k0 + q * 8];
#pragma unroll
        for (int mt = 0; mt < 4; mt++)
#pragma unroll
            for (int nt = 0; nt < 2; nt++)
                acc[mt][nt] = __builtin_amdgcn_mfma_f32_16x16x32_bf16(af[mt], bfr[nt], acc[mt][nt], 0, 0, 0);
    }

#pragma unroll
    for (int mt = 0; mt < 4; mt++)
#pragma unroll
        for (int i = 0; i < 4; i++) {
            int row = mt * 16 + q * 4 + i;
            int n = nbase + row;
            if (n < N) {
#pragma unroll
                for (int nt = 0; nt < 2; nt++) {
                    int o = w * 32 + nt * 16 + m;
                    float v = acc[mt][nt][i];
                    if (relu) v = fmaxf(v, 0.f);
                    if (out16) out16[(size_t)n * D + o] = (bf16_t)v;
                    else       out32[(size_t)n * D + o] = v;
                }
            }
        }
}

// standalone root (fallback path only): out = (relu?)( x @ root + agg )
__global__ __launch_bounds__(256, 3)
void root_gemm(const bf16_t* x, const bf16_t* __restrict__ roott,
               const float* __restrict__ agg, bf16_t* out16, float* out32,
               int N, int relu) {
    __shared__ bf16_t sW[D * DPAD];
    __shared__ bf16_t sA[64 * DPAD];
    int tid = threadIdx.x;
    int nbase = blockIdx.x * 64;

    const uint4* Wg = (const uint4*)roott;
    for (int c = tid; c < D * 16; c += 256) {
        int row = c >> 4, col = c & 15;
        *(uint4*)&sW[row * DPAD + col * 8] = Wg[c];
    }
    for (int c = tid; c < 64 * 16; c += 256) {
        int row = c >> 4, col = c & 15;
        int n = nbase + row;
        if (n >= N) n = N - 1;
        *(uint4*)&sA[row * DPAD + col * 8] = ((const uint4*)(x + (size_t)n * D))[col];
    }
    __syncthreads();

    int lane = tid & 63;
    int w = tid >> 6;
    int m = lane & 15, q = lane >> 4;
    f32x4 acc[4][2];
#pragma unroll
    for (int a = 0; a < 4; a++)
#pragma unroll
        for (int b = 0; b < 2; b++) acc[a][b] = (f32x4){0.f, 0.f, 0.f, 0.f};

#pragma unroll
    for (int k0 = 0; k0 < D; k0 += 32) {
        bf16x8 af[4], bfr[2];
#pragma unroll
        for (int mt = 0; mt < 4; mt++)
            af[mt] = *(const bf16x8*)&sA[(mt * 16 + m) * DPAD + k0 + q * 8];
#pragma unroll
        for (int nt = 0; nt < 2; nt++)
            bfr[nt] = *(const bf16x8*)&sW[(w * 32 + nt * 16 + m) * DPAD + k0 + q * 8];
#pragma unroll
        for (int mt = 0; mt < 4; mt++)
#pragma unroll
            for (int nt = 0; nt < 2; nt++)
                acc[mt][nt] = __builtin_amdgcn_mfma_f32_16x16x32_bf16(af[mt], bfr[nt], acc[mt][nt], 0, 0, 0);
    }

#pragma unroll
    for (int mt = 0; mt < 4; mt++)
#pragma unroll
        for (int i = 0; i < 4; i++) {
            int row = mt * 16 + q * 4 + i;
            int n = nbase + row;
            if (n < N) {
#pragma unroll
                for (int nt = 0; nt < 2; nt++) {
                    int o = w * 32 + nt * 16 + m;
                    float v = acc[mt][nt][i] + agg[(size_t)n * D + o];
                    if (relu) v = fmaxf(v, 0.f);
                    if (out16) out16[(size_t)n * D + o] = (bf16_t)v;
                    else       out32[(size_t)n * D + o] = v;
                }
            }
        }
}

// ---------------- host launcher ----------------

extern "C" void kernel_launch(void* const* d_in, const int* in_sizes, int n_in,
                              void* d_out, int out_size, void* d_ws, size_t ws_size,
                              hipStream_t stream) {
    const int*   entity = (const int*)d_in[0];
    const int*   ei     = (const int*)d_in[1];   // [2,E]: row0=src, row1=dst
    const int*   et     = (const int*)d_in[2];
    const float* emb    = (const float*)d_in[4];
    const float* W1     = (const float*)d_in[5];
    const float* root1  = (const float*)d_in[6];
    const float* W2     = (const float*)d_in[7];
    const float* root2  = (const float*)d_in[8];

    const int N = in_sizes[0];
    const int E = in_sizes[2];
    const int R = in_sizes[5] / (D * D);

    char* p = (char*)d_ws;
    auto alloc = [&](size_t bytes) -> char* {
        char* q = p; p += (bytes + 255) & ~(size_t)255; return q;
    };
    // common region
    float*  agg      = (float*)alloc((size_t)N * D * 4);
    bf16_t* x        = (bf16_t*)alloc((size_t)N * D * 2);
    bf16_t* Wt       = (bf16_t*)alloc((size_t)(2 * R + 2) * D * D * 2);
    int*    s_src    = (int*)alloc((size_t)E * 4);
    int*    cnt      = (int*)alloc((size_t)N * 4);
    float*  inv      = (float*)alloc((size_t)N * 4);
    int*    blockhist= (int*)alloc((size_t)NB * R * 4);
    int*    blockoff = (int*)alloc((size_t)NB * R * 4);
    int*    rel_off  = (int*)alloc((size_t)(R + 1) * 4);
    int*    tile_bs  = (int*)alloc((size_t)(R + 1) * 4);
    const int maxtiles = (E + TME - 1) / TME + R;
    int*    tile_rel = (int*)alloc((size_t)maxtiles * 4);
    int*    tile_idx = (int*)alloc((size_t)maxtiles * 4);
    char*   p_common = p;

    // scatter-path extras
    bf16_t* msgs    = (bf16_t*)alloc((size_t)E * D * 2);
    int*    relpos  = (int*)alloc((size_t)E * 4);
    int*    msgpos  = (int*)alloc((size_t)E * 4);
    int*    dst_off = (int*)alloc((size_t)(N + 1) * 4);
    int*    dst_ptr = (int*)alloc((size_t)N * 4);
    int*    bsum    = (int*)alloc((size_t)(NSB + 1) * 4);
    bool big = ((size_t)(p - (char*)d_ws) <= ws_size);

    int* s_dst = nullptr;
    if (!big) { p = p_common; s_dst = (int*)alloc((size_t)E * 4); }

    const int chunk = (E + NB - 1) / NB;

    // shared preprocessing
    hipMemsetAsync(cnt, 0, (size_t)N * 4, stream);
    hist_kernel<<<NB, 256, 0, stream>>>(ei, et, E, chunk, R, blockhist, cnt);
    scan_kernel<<<1, 256, 0, stream>>>(blockhist, R, blockoff, rel_off, tile_bs, tile_rel, tile_idx);
    scatter2_kernel<<<NB, 256, 0, stream>>>(ei, et, E, chunk, R, blockoff,
                                            s_src, big ? nullptr : s_dst, big ? relpos : nullptr);
    transpose_kernel<<<2 * R + 2, 256, 0, stream>>>(W1, root1, W2, root2, R, Wt);
    gather_kernel<<<(N * 16 + 255) / 256, 256, 0, stream>>>(entity, emb, x, N);

    if (big) {
        const int chunkN = (N + NSB - 1) / NSB;
        nsum_kernel<<<NSB, NST, 0, stream>>>(cnt, N, chunkN, bsum);
        nscanB_kernel<<<1, NST, 0, stream>>>(bsum, NSB);
        nwrite_kernel<<<NSB, NST, 0, stream>>>(cnt, N, chunkN, bsum, dst_off, dst_ptr);
        dstclaim_kernel<<<(E + 255) / 256, 256, 0, stream>>>(ei, E, dst_ptr, relpos, msgpos);

        // layer 1
        edge_gemm_scatter<<<maxtiles, 256, 0, stream>>>(x, Wt, s_src, msgpos,
                                                        rel_off, tile_bs, tile_rel, tile_idx, R, msgs);
        seg_root_gemm<<<(N + 63) / 64, 256, 0, stream>>>(msgs, dst_off, x,
                                                         Wt + (size_t)(2 * R) * D * D,
                                                         x, (float*)nullptr, N, 1);
        // layer 2
        edge_gemm_scatter<<<maxtiles, 256, 0, stream>>>(x, Wt + (size_t)R * D * D, s_src, msgpos,
                                                        rel_off, tile_bs, tile_rel, tile_idx, R, msgs);
        seg_root_gemm<<<(N + 63) / 64, 256, 0, stream>>>(msgs, dst_off, x,
                                                         Wt + (size_t)(2 * R + 1) * D * D,
                                                         (bf16_t*)nullptr, (float*)d_out, N, 0);
    } else {
        // atomic fallback
        inv_kernel<<<(N + 255) / 256, 256, 0, stream>>>(cnt, inv, N);
        hipMemsetAsync(agg, 0, (size_t)N * D * 4, stream);
        edge_gemm_atomic<<<maxtiles, 256, 0, stream>>>(x, Wt, s_src, s_dst, inv,
                                                       rel_off, tile_bs, tile_rel, tile_idx, R, agg);
        root_gemm<<<(N + 63) / 64, 256, 0, stream>>>(x, Wt + (size_t)(2 * R) * D * D, agg,
                                                     x, (float*)nullptr, N, 1);
        hipMemsetAsync(agg, 0, (size_t)N * D * 4, stream);
        edge_gemm_atomic<<<maxtiles, 256, 0, stream>>>(x, Wt + (size_t)R * D * D, s_src, s_dst, inv,
                                                       rel_off, tile_bs, tile_rel, tile_idx, R, agg);
        root_gemm<<<(N + 63) / 64, 256, 0, stream>>>(x, Wt + (size_t)(2 * R + 1) * D * D, agg,
                                                     (bf16_t*)nullptr, (float*)d_out, N, 0);
    }
}